// Round 2
// baseline (1885.986 us; speedup 1.0000x reference)
//
#include <hip/hip_runtime.h>

typedef unsigned int uint_t;
typedef _Float16 h2 __attribute__((ext_vector_type(2)));

#define NPTS 1024
#define DIM  128
#define NH2  64          // half2 words per point
#define NTHR 512
#define NW   8           // waves per block
#define PPT  2           // points per thread

__device__ __forceinline__ float dot2f(uint_t a, uint_t b, float c) {
#if __has_builtin(__builtin_amdgcn_fdot2)
    return __builtin_amdgcn_fdot2(__builtin_bit_cast(h2, a),
                                  __builtin_bit_cast(h2, b), c, false);
#else
    h2 ha = __builtin_bit_cast(h2, a);
    h2 hb = __builtin_bit_cast(h2, b);
    c += (float)ha[0] * (float)hb[0];
    c += (float)ha[1] * (float)hb[1];
    return c;
#endif
}

__device__ __forceinline__ uint_t umin_u(uint_t a, uint_t b) { return a < b ? a : b; }

// One block (512 threads = 8 waves) per sample; thread t owns points 2t, 2t+1
// (fp16-packed coords in VGPRs). Prim's MST with ONE barrier per step:
// each wave speculatively publishes its local argmin candidate (coords, norm,
// exact death) into a double-buffered per-wave LDS slot BEFORE the barrier;
// after the barrier all threads min the 8 wave keys and simply INDEX the
// winning wave's slot next iteration.
__global__ __launch_bounds__(NTHR, 2)
void prim_mst_kernel(const float* __restrict__ reps, float* __restrict__ out,
                     float scale) {
    const int s    = blockIdx.x;
    const int t    = threadIdx.x;
    const int lane = t & 63;
    const int wave = t >> 6;

    __shared__ uint4  sc[2][NW][NH2 / 4];  // per-wave candidate coords (double-buffered)
    __shared__ float  snrm[2][NW];         // candidate norm
    __shared__ float  sdth[2][NW];         // candidate exact death (d^2)
    __shared__ uint4  warr[2][2];          // 8 packed keys per parity, as 2x uint4

    // ---- load my 2 points, quantize to fp16, norms of quantized coords ----
    uint_t cx[PPT][NH2];
    float  nrm[PPT], mind[PPT];
#pragma unroll
    for (int p = 0; p < PPT; ++p) {
        const float4* src = (const float4*)(reps + (size_t)s * (NPTS * DIM) +
                                            (size_t)(PPT * t + p) * DIM);
        float n = 0.f;
#pragma unroll
        for (int k = 0; k < 32; ++k) {
            float4 v = src[k];
            h2 a; a[0] = (_Float16)v.x; a[1] = (_Float16)v.y;
            h2 b; b[0] = (_Float16)v.z; b[1] = (_Float16)v.w;
            cx[p][2 * k]     = __builtin_bit_cast(uint_t, a);
            cx[p][2 * k + 1] = __builtin_bit_cast(uint_t, b);
            n = dot2f(cx[p][2 * k], cx[p][2 * k], n);
            n = dot2f(cx[p][2 * k + 1], cx[p][2 * k + 1], n);
        }
        nrm[p]  = n;
        mind[p] = 3.0e38f;
    }

    uint_t vis = 0;
    if (t == 0) {   // seed: point 0 is the tree root
#pragma unroll
        for (int k = 0; k < NH2 / 4; ++k)
            sc[0][0][k] = make_uint4(cx[0][4 * k], cx[0][4 * k + 1],
                                     cx[0][4 * k + 2], cx[0][4 * k + 3]);
        snrm[0][0] = nrm[0];
        vis = 1;
    }
    __syncthreads();

    int   rp = 0, curw = 0;
    float acc = 0.f;

    for (int it = 0; it < NPTS - 1; ++it) {
        // ---- (1) distances of my 2 points to current frontier point ----
        const uint4* q  = sc[rp][curw];
        const float  bn = snrm[rp][curw];
        float a00 = 0.f, a01 = 0.f, a02 = 0.f, a03 = 0.f;
        float a10 = 0.f, a11 = 0.f, a12 = 0.f, a13 = 0.f;
#pragma unroll
        for (int k = 0; k < NH2 / 4; ++k) {
            uint4 qq = q[k];
            a00 = dot2f(cx[0][4 * k + 0], qq.x, a00);
            a01 = dot2f(cx[0][4 * k + 1], qq.y, a01);
            a02 = dot2f(cx[0][4 * k + 2], qq.z, a02);
            a03 = dot2f(cx[0][4 * k + 3], qq.w, a03);
            a10 = dot2f(cx[1][4 * k + 0], qq.x, a10);
            a11 = dot2f(cx[1][4 * k + 1], qq.y, a11);
            a12 = dot2f(cx[1][4 * k + 2], qq.z, a12);
            a13 = dot2f(cx[1][4 * k + 3], qq.w, a13);
        }
        float d20 = fmaxf(bn + nrm[0] - 2.f * ((a00 + a01) + (a02 + a03)), 0.f);
        float d21 = fmaxf(bn + nrm[1] - 2.f * ((a10 + a11) + (a12 + a13)), 0.f);
        mind[0] = fminf(mind[0], d20);
        mind[1] = fminf(mind[1], d21);

        // ---- (2) wave argmin over packed keys (dist | point index) ----
        uint_t k0 = (vis & 1u) ? 0xFFFFFFFFu
                  : ((__float_as_uint(mind[0]) & 0xFFFFFC00u) | (uint_t)(2 * t));
        uint_t k1 = (vis & 2u) ? 0xFFFFFFFFu
                  : ((__float_as_uint(mind[1]) & 0xFFFFFC00u) | (uint_t)(2 * t + 1));
        uint_t key = umin_u(k0, k1);
#pragma unroll
        for (int m = 32; m >= 1; m >>= 1)
            key = umin_u(key, (uint_t)__shfl_xor((int)key, m, 64));

        // ---- (3) speculative publish of this wave's candidate ----
        const int wp = rp ^ 1;
        const int wj = (int)(key & 0x3FFu);
        if ((wj >> 1) == t) {
            const int ps = wj & 1;
#pragma unroll
            for (int k = 0; k < NH2 / 4; ++k) {
                uint_t e0 = ps ? cx[1][4 * k + 0] : cx[0][4 * k + 0];
                uint_t e1 = ps ? cx[1][4 * k + 1] : cx[0][4 * k + 1];
                uint_t e2 = ps ? cx[1][4 * k + 2] : cx[0][4 * k + 2];
                uint_t e3 = ps ? cx[1][4 * k + 3] : cx[0][4 * k + 3];
                sc[wp][wave][k] = make_uint4(e0, e1, e2, e3);
            }
            snrm[wp][wave] = ps ? nrm[1] : nrm[0];
            sdth[wp][wave] = ps ? mind[1] : mind[0];
        }
        if (lane == 0) ((uint_t*)&warr[wp][0])[wave] = key;

        __syncthreads();   // the ONE barrier per step

        // ---- (4) global argmin from the 8 wave keys ----
        uint4 wv0 = warr[wp][0], wv1 = warr[wp][1];
        uint_t g = umin_u(umin_u(umin_u(wv0.x, wv0.y), umin_u(wv0.z, wv0.w)),
                          umin_u(umin_u(wv1.x, wv1.y), umin_u(wv1.z, wv1.w)));
        const int j = (int)(g & 0x3FFu);
        curw = j >> 7;                       // winner's wave
        if ((j >> 1) == t) vis |= 1u << (j & 1);
        if (t == 0) acc += sqrtf(sdth[wp][curw]);
        rp = wp;
    }

    if (t == 0) atomicAdd(out, acc * scale);
}

extern "C" void kernel_launch(void* const* d_in, const int* in_sizes, int n_in,
                              void* d_out, int out_size, void* d_ws, size_t ws_size,
                              hipStream_t stream) {
    const float* reps = (const float*)d_in[0];
    float*       out  = (float*)d_out;
    const int b = in_sizes[0] / (NPTS * DIM);   // batch size (128)

    // loss = sum_s( mean_s ) / (b * 2); mean_s = sum_deaths / (NPTS-1)
    const float scale = 1.0f / ((float)(NPTS - 1) * (float)b * 2.0f);

    hipMemsetAsync(out, 0, sizeof(float), stream);
    prim_mst_kernel<<<dim3(b), dim3(NTHR), 0, stream>>>(reps, out, scale);
}

// Round 3
// 1721.845 us; speedup vs baseline: 1.0953x; 1.0953x over previous
//
#include <hip/hip_runtime.h>

typedef unsigned int uint_t;
typedef _Float16 h2 __attribute__((ext_vector_type(2)));

#define NPTS 1024
#define DIM  128
#define NH2  64          // half2 words per point
#define NTHR 256
#define NWAVE 4
#define PPT  4           // points per thread: t, t+256, t+512, t+768

__device__ __forceinline__ float dot2f(uint_t a, uint_t b, float c) {
#if __has_builtin(__builtin_amdgcn_fdot2)
    return __builtin_amdgcn_fdot2(__builtin_bit_cast(h2, a),
                                  __builtin_bit_cast(h2, b), c, false);
#else
    h2 ha = __builtin_bit_cast(h2, a);
    h2 hb = __builtin_bit_cast(h2, b);
    c += (float)ha[0] * (float)hb[0];
    c += (float)ha[1] * (float)hb[1];
    return c;
#endif
}

__device__ __forceinline__ uint_t umin_u(uint_t a, uint_t b) { return a < b ? a : b; }

// 64-lane min-reduce in ~6 VALU-latency steps via DPP (vs ~600cyc ds_swizzle).
// Result accumulates toward lane 63. old=x + bound_ctrl=false => invalid
// source lanes yield min(x,x)=x (safe identity).
#define DPP_UMIN(x, ctrl)                                                       \
    x = umin_u(x, (uint_t)__builtin_amdgcn_update_dpp((int)(x), (int)(x),       \
                                                      (ctrl), 0xf, 0xf, false))

// One block (256 threads = 4 waves, 1 wave/SIMD) per sample. Thread t owns
// points {t, t+256, t+512, t+768}, fp16-packed in VGPRs (~300 VGPRs).
// Prim's MST: 1023 steps, each = dots -> DPP wave argmin -> barrier ->
// 4-key min -> winner publishes coords (uniform branch, no cndmask) -> barrier.
__global__ __launch_bounds__(NTHR, 1)
void prim_mst_kernel(const float* __restrict__ reps, float* __restrict__ out,
                     float scale) {
    const int s    = blockIdx.x;
    const int t    = threadIdx.x;
    const int lane = t & 63;
    const int wave = t >> 6;

    __shared__ uint4  sc[NH2 / 4];                 // frontier point coords
    __shared__ float  snrm;                        // frontier point norm
    __shared__ __align__(16) uint_t warr[NWAVE];   // per-wave argmin keys
    __shared__ float  facc[NWAVE];                 // final sum reduce

    // ---- load my 4 points, quantize to fp16, norms ----
    uint_t cx[PPT][NH2];
    float  nrm[PPT], mind[PPT];
#pragma unroll
    for (int p = 0; p < PPT; ++p) {
        const float4* src = (const float4*)(reps + (size_t)s * (NPTS * DIM) +
                                            (size_t)(p * NTHR + t) * DIM);
        float n = 0.f;
#pragma unroll
        for (int k = 0; k < 32; ++k) {
            float4 v = src[k];
            h2 a; a[0] = (_Float16)v.x; a[1] = (_Float16)v.y;
            h2 b; b[0] = (_Float16)v.z; b[1] = (_Float16)v.w;
            cx[p][2 * k]     = __builtin_bit_cast(uint_t, a);
            cx[p][2 * k + 1] = __builtin_bit_cast(uint_t, b);
            n = dot2f(cx[p][2 * k], cx[p][2 * k], n);
            n = dot2f(cx[p][2 * k + 1], cx[p][2 * k + 1], n);
        }
        nrm[p]  = n;
        mind[p] = 3.0e38f;
    }

    uint_t vis = 0;
    if (t == 0) {   // seed: point 0 (p=0 of thread 0) is the root
#pragma unroll
        for (int k = 0; k < NH2 / 4; ++k)
            sc[k] = make_uint4(cx[0][4 * k], cx[0][4 * k + 1],
                               cx[0][4 * k + 2], cx[0][4 * k + 3]);
        snrm = nrm[0];
        vis  = 1;
    }
    __syncthreads();

    float acc = 0.f;   // sum of sqrt(death) for edges THIS thread won

    for (int it = 0; it < NPTS - 1; ++it) {
        // ---- (1) distances of my 4 points to the frontier point ----
        const float bn = snrm;
        float e0[PPT], e1[PPT];
#pragma unroll
        for (int p = 0; p < PPT; ++p) { e0[p] = 0.f; e1[p] = 0.f; }
#pragma unroll
        for (int k = 0; k < NH2 / 4; ++k) {
            uint4 q = sc[k];   // broadcast read
#pragma unroll
            for (int p = 0; p < PPT; ++p) {
                e0[p] = dot2f(cx[p][4 * k + 0], q.x, e0[p]);
                e1[p] = dot2f(cx[p][4 * k + 1], q.y, e1[p]);
                e0[p] = dot2f(cx[p][4 * k + 2], q.z, e0[p]);
                e1[p] = dot2f(cx[p][4 * k + 3], q.w, e1[p]);
            }
        }
        uint_t key = 0xFFFFFFFFu;
#pragma unroll
        for (int p = 0; p < PPT; ++p) {
            float d2 = fmaxf(bn + nrm[p] - 2.f * (e0[p] + e1[p]), 0.f);
            mind[p]  = fminf(mind[p], d2);
            uint_t kp = ((vis >> p) & 1u)
                      ? 0xFFFFFFFFu
                      : ((__float_as_uint(mind[p]) & 0xFFFFFC00u) |
                         (uint_t)(p * NTHR + t));
            key = umin_u(key, kp);
        }

        // ---- (2) wave argmin via DPP (pure VALU, ~50 cyc) ----
        DPP_UMIN(key, 0x111);   // row_shr:1
        DPP_UMIN(key, 0x112);   // row_shr:2
        DPP_UMIN(key, 0x114);   // row_shr:4
        DPP_UMIN(key, 0x118);   // row_shr:8
        DPP_UMIN(key, 0x142);   // row_bcast:15
        DPP_UMIN(key, 0x143);   // row_bcast:31 -> lane 63 has wave min
        uint_t wkey = (uint_t)__builtin_amdgcn_readlane((int)key, 63);
        if (lane == 0) warr[wave] = wkey;
        __syncthreads();

        // ---- (3) global argmin from 4 wave keys; winner publishes ----
        uint4  wv = *(const uint4*)warr;
        uint_t g  = umin_u(umin_u(wv.x, wv.y), umin_u(wv.z, wv.w));
        const int j  = (int)(g & 0x3FFu);
        const int jp = j >> 8;            // block-uniform: which p slot
        if ((j & (NTHR - 1)) == t) {      // exactly one thread
#pragma unroll
            for (int p = 0; p < PPT; ++p) {
                if (jp == p) {            // uniform branch, no cndmask select
#pragma unroll
                    for (int k = 0; k < NH2 / 4; ++k)
                        sc[k] = make_uint4(cx[p][4 * k], cx[p][4 * k + 1],
                                           cx[p][4 * k + 2], cx[p][4 * k + 3]);
                    snrm = nrm[p];
                    acc += sqrtf(mind[p]);
                }
            }
            vis |= 1u << jp;
        }
        __syncthreads();
    }

    // ---- final: block sum of per-thread acc ----
#pragma unroll
    for (int m = 32; m >= 1; m >>= 1) acc += __shfl_xor(acc, m, 64);
    if (lane == 0) facc[wave] = acc;
    __syncthreads();
    if (t == 0)
        atomicAdd(out, (facc[0] + facc[1] + facc[2] + facc[3]) * scale);
}

extern "C" void kernel_launch(void* const* d_in, const int* in_sizes, int n_in,
                              void* d_out, int out_size, void* d_ws, size_t ws_size,
                              hipStream_t stream) {
    const float* reps = (const float*)d_in[0];
    float*       out  = (float*)d_out;
    const int b = in_sizes[0] / (NPTS * DIM);   // batch size (128)

    // loss = sum_s( mean_s ) / (b * 2); mean_s = sum_deaths / (NPTS-1)
    const float scale = 1.0f / ((float)(NPTS - 1) * (float)b * 2.0f);

    hipMemsetAsync(out, 0, sizeof(float), stream);
    prim_mst_kernel<<<dim3(b), dim3(NTHR), 0, stream>>>(reps, out, scale);
}